// Round 3
// baseline (384.804 us; speedup 1.0000x reference)
//
#include <hip/hip_runtime.h>

// B=4096 batches, D=100 features, T=100 timesteps, O=3 outputs.
#define NB 4096
#define ND 100
#define NT 100
#define NO 3
#define CPITCH 101   // cur_s pitch: stride-1 lane writes per o-plane, conflict-free

// One block per batch b, 128 threads (2 waves).
// Phase 0: stage W into LDS as Ws[p][o][j] = W[o][4p+j] (wave-uniform broadcast reads).
// Phase 1: thread t (t<100) owns row t: reads 25 float4 of x,u (rows are 400 B,
//   16B-aligned), forms spikes in-register, FMAs against broadcast W. No shuffles,
//   no cross-lane reduce; ~50 independent global loads per thread -> deep vmcnt queue.
//   Lanes of a wave read 64 adjacent rows -> block streams a contiguous 80 KB region.
// Phase 2: threads 0..2 run the sequential leaky scan from LDS, writing spk/mem
//   directly to global (12 B contiguous per (t,block)).
__global__ __launch_bounds__(128) void fused_leaky(
    const float* __restrict__ x, const float* __restrict__ u,
    const float* __restrict__ W, const float* __restrict__ bias,
    const float* __restrict__ beta_p, const float* __restrict__ thr_p,
    float* __restrict__ out)
{
    __shared__ float Ws[25][NO][4];      // [p][o][j] = W[o][4p+j], 1.2 KB
    __shared__ float cur_s[NO][CPITCH];  // [o][t]

    const int b   = blockIdx.x;
    const int tid = threadIdx.x;

    // Stage W (300 floats) via float4; one-time cost.
    if (tid < 75) {
        const int o = tid / 25;
        const int p = tid - o * 25;
        const float4 w = ((const float4*)(W + o * ND))[p];
        Ws[p][o][0] = w.x; Ws[p][o][1] = w.y; Ws[p][o][2] = w.z; Ws[p][o][3] = w.w;
    }
    __syncthreads();

    if (tid < NT) {
        const float4* xr = (const float4*)(x + (size_t)b * (ND * ND) + tid * ND);
        const float4* ur = (const float4*)(u + (size_t)b * (ND * ND) + tid * ND);
        float a0 = 0.f, a1 = 0.f, a2 = 0.f;
        #pragma unroll 5
        for (int p = 0; p < 25; ++p) {
            const float4 xv = xr[p];
            const float4 uv = ur[p];
            const float s0 = (uv.x < xv.x) ? 1.f : 0.f;
            const float s1 = (uv.y < xv.y) ? 1.f : 0.f;
            const float s2 = (uv.z < xv.z) ? 1.f : 0.f;
            const float s3 = (uv.w < xv.w) ? 1.f : 0.f;
            a0 = fmaf(s3, Ws[p][0][3], fmaf(s2, Ws[p][0][2], fmaf(s1, Ws[p][0][1], fmaf(s0, Ws[p][0][0], a0))));
            a1 = fmaf(s3, Ws[p][1][3], fmaf(s2, Ws[p][1][2], fmaf(s1, Ws[p][1][1], fmaf(s0, Ws[p][1][0], a1))));
            a2 = fmaf(s3, Ws[p][2][3], fmaf(s2, Ws[p][2][2], fmaf(s1, Ws[p][2][1], fmaf(s0, Ws[p][2][0], a2))));
        }
        cur_s[0][tid] = a0;   // lanes stride-1 within each o-plane: conflict-free
        cur_s[1][tid] = a1;
        cur_s[2][tid] = a2;
    }
    __syncthreads();

    // Sequential leaky scan: threads 0..2, o = tid.
    if (tid < NO) {
        const int   o    = tid;
        const float beta = beta_p[0];
        const float thr  = thr_p[0];
        const float bo   = bias[o];
        const int   col  = b * NO + o;
        float* mem_rec = out + (size_t)NT * NB * NO;

        float mem = 0.f;
        #pragma unroll 4
        for (int t = 0; t < NT; ++t) {
            const float cv   = cur_s[o][t] + bo;          // fc1 + bias
            const float rsub = (mem > thr) ? thr : 0.f;   // reset from PREV mem
            // match numpy elementwise order: (beta*mem + cur) - reset*thr, no FMA fusion
            mem = __fadd_rn(__fadd_rn(__fmul_rn(beta, mem), cv), -rsub);
            const float s = (mem > thr) ? 1.f : 0.f;
            out[(size_t)t * (NB * NO) + col]     = s;
            mem_rec[(size_t)t * (NB * NO) + col] = mem;
        }
    }
}

extern "C" void kernel_launch(void* const* d_in, const int* in_sizes, int n_in,
                              void* d_out, int out_size, void* d_ws, size_t ws_size,
                              hipStream_t stream) {
    const float* x    = (const float*)d_in[0];   // [4096,100,100]
    const float* u    = (const float*)d_in[1];   // [4096,100,100]
    const float* W    = (const float*)d_in[2];   // [3,100]
    const float* bias = (const float*)d_in[3];   // [3]
    const float* beta = (const float*)d_in[4];   // scalar
    const float* thr  = (const float*)d_in[5];   // scalar
    float* out = (float*)d_out;

    fused_leaky<<<NB, 128, 0, stream>>>(x, u, W, bias, beta, thr, out);
}

// Round 4
// 354.672 us; speedup vs baseline: 1.0850x; 1.0850x over previous
//
#include <hip/hip_runtime.h>

// B=4096 batches, D=100 features, T=100 timesteps, O=3 outputs.
#define NB 4096
#define ND 100
#define NT 100
#define NO 3
#define CPITCH 101   // cur_s row pitch (free of conflicts for the 3-thread scan)

// One block per batch, 320 threads = 5 waves = 10 half-waves.
// Half-wave hw owns rows t = i*10 + hw, i = 0..9. Lanes 0..24 of the half each
// load one float4 of x,u (row = 25 float4s = 400 B, 16B-aligned); lanes 25..31
// load a clamped duplicate (same cache line -> coalesced, zero weights -> exact 0
// contribution). A wave covers rows (2w, 2w+1): contiguous 800 B = 7 cache lines.
// Manual depth-1 prefetch + full unroll keeps >=4 loads in flight per wave.
// Reduction: 5 __shfl_xor steps (masks 16..1 stay within each 32-lane half),
// 3 independent chains interleaved for latency hiding.
// Tail: threads 0..2 run the sequential leaky scan from LDS.
__global__ __launch_bounds__(320) void fused_leaky(
    const float* __restrict__ x, const float* __restrict__ u,
    const float* __restrict__ W, const float* __restrict__ bias,
    const float* __restrict__ beta_p, const float* __restrict__ thr_p,
    float* __restrict__ out)
{
    __shared__ float cur_s[NO][CPITCH];

    const int b   = blockIdx.x;
    const int tid = threadIdx.x;
    const int hw  = tid >> 5;              // half-wave 0..9
    const int l   = tid & 31;
    const int pc  = (l < 25) ? l : 24;     // clamped float4 index within the row

    // Register-resident weight fragments; zero for the 7 clamped lanes.
    float4 w0 = {0,0,0,0}, w1 = {0,0,0,0}, w2 = {0,0,0,0};
    if (l < 25) {
        w0 = ((const float4*)(W         ))[l];
        w1 = ((const float4*)(W +    ND ))[l];
        w2 = ((const float4*)(W + 2*ND  ))[l];
    }

    const float4* xp = (const float4*)(x + (size_t)b * (ND * ND) + hw * ND) + pc;
    const float4* up = (const float4*)(u + (size_t)b * (ND * ND) + hw * ND) + pc;

    float4 xv = *xp;                       // prefetch iteration 0
    float4 uv = *up;

    #pragma unroll
    for (int i = 0; i < 10; ++i) {
        const float4 xc = xv, uc = uv;
        if (i < 9) {                       // uniform guard; prefetch next rows
            xp += 250; up += 250;          // +10 rows = +1000 floats
            xv = *xp;  uv = *up;
        }
        const float s0 = (uc.x < xc.x) ? 1.f : 0.f;
        const float s1 = (uc.y < xc.y) ? 1.f : 0.f;
        const float s2 = (uc.z < xc.z) ? 1.f : 0.f;
        const float s3 = (uc.w < xc.w) ? 1.f : 0.f;
        float a0 = fmaf(s3, w0.w, fmaf(s2, w0.z, fmaf(s1, w0.y, s0 * w0.x)));
        float a1 = fmaf(s3, w1.w, fmaf(s2, w1.z, fmaf(s1, w1.y, s0 * w1.x)));
        float a2 = fmaf(s3, w2.w, fmaf(s2, w2.z, fmaf(s1, w2.y, s0 * w2.x)));
        #pragma unroll
        for (int m = 16; m >= 1; m >>= 1) {   // stays within each 32-lane half
            a0 += __shfl_xor(a0, m);
            a1 += __shfl_xor(a1, m);
            a2 += __shfl_xor(a2, m);
        }
        if (l == 0) {
            const int t = i * 10 + hw;
            cur_s[0][t] = a0;
            cur_s[1][t] = a1;
            cur_s[2][t] = a2;
        }
    }
    __syncthreads();

    // Sequential leaky scan: threads 0..2, o = tid.
    if (tid < NO) {
        const int   o    = tid;
        const float beta = beta_p[0];
        const float thr  = thr_p[0];
        const float bo   = bias[o];
        const int   col  = b * NO + o;
        float* mem_rec = out + (size_t)NT * NB * NO;

        float mem = 0.f;
        #pragma unroll 10
        for (int t = 0; t < NT; ++t) {
            const float cv   = cur_s[o][t] + bo;          // fc1 + bias
            const float rsub = (mem > thr) ? thr : 0.f;   // reset from PREV mem
            // match numpy elementwise order: (beta*mem + cur) - reset*thr, no FMA fusion
            mem = __fadd_rn(__fadd_rn(__fmul_rn(beta, mem), cv), -rsub);
            const float s = (mem > thr) ? 1.f : 0.f;
            out[(size_t)t * (NB * NO) + col]     = s;
            mem_rec[(size_t)t * (NB * NO) + col] = mem;
        }
    }
}

extern "C" void kernel_launch(void* const* d_in, const int* in_sizes, int n_in,
                              void* d_out, int out_size, void* d_ws, size_t ws_size,
                              hipStream_t stream) {
    const float* x    = (const float*)d_in[0];   // [4096,100,100]
    const float* u    = (const float*)d_in[1];   // [4096,100,100]
    const float* W    = (const float*)d_in[2];   // [3,100]
    const float* bias = (const float*)d_in[3];   // [3]
    const float* beta = (const float*)d_in[4];   // scalar
    const float* thr  = (const float*)d_in[5];   // scalar
    float* out = (float*)d_out;

    fused_leaky<<<NB, 320, 0, stream>>>(x, u, W, bias, beta, thr, out);
}